// Round 4
// baseline (408.422 us; speedup 1.0000x reference)
//
#include <hip/hip_runtime.h>

typedef __bf16 bf16;
typedef bf16 bf16x8 __attribute__((ext_vector_type(8)));
typedef bf16 bf16x4 __attribute__((ext_vector_type(4)));
typedef float f32x4 __attribute__((ext_vector_type(4)));

__device__ __forceinline__ bf16x8 cvt2(const float4 a, const float4 b) {
    bf16x8 t;
    t[0] = (bf16)a.x; t[1] = (bf16)a.y; t[2] = (bf16)a.z; t[3] = (bf16)a.w;
    t[4] = (bf16)b.x; t[5] = (bf16)b.y; t[6] = (bf16)b.z; t[7] = (bf16)b.w;
    return t;
}

// =====================================================================
// GEMM: C[M,N] = A[M,K=1024] * W[N,K=1024]^T   (row-major, K contig)
// M=8192, N=1024. grid (N/128, M/128), block 256 (4 waves, 2x2 of 64x64).
// All external tensors fp32 (converted to bf16 in staging).
// MODE 0: A fp32, out bf16 [B,H,S,d]   (Q/K projection)
// MODE 1: A fp32, out bf16 [B,H,d,S]   (V projection, transposed)
// MODE 2: A bf16 internal (ctx), out fp32 [M,N] = acc + R (fp32 residual)
// =====================================================================
template<int MODE>
__global__ __launch_bounds__(256, 2)
void gemm_bt(const void* __restrict__ Ap, const float* __restrict__ W,
             const float* __restrict__ R, void* __restrict__ outp)
{
    constexpr int K = 1024;
    constexpr int BK = 32;
    __shared__ __align__(16) bf16 As[128 * BK];
    __shared__ __align__(16) bf16 Bs[128 * BK];

    const int tid  = threadIdx.x;
    const int lane = tid & 63;
    const int w    = tid >> 6;
    const int wr   = w >> 1, wc = w & 1;
    const int m0   = blockIdx.y * 128;
    const int n0   = blockIdx.x * 128;

    f32x4 acc[4][4] = {};

    for (int k0 = 0; k0 < K; k0 += BK) {
        #pragma unroll
        for (int i = 0; i < 2; ++i) {
            const int c   = w * 128 + i * 64 + lane;
            const int row = c >> 2, kg = c & 3;
            const float* wp = W + (size_t)(n0 + row) * K + k0 + kg * 8;
            *(bf16x8*)&Bs[c * 8] = cvt2(*(const float4*)wp, *(const float4*)(wp + 4));
            if constexpr (MODE == 2) {
                const bf16* ap = (const bf16*)Ap + (size_t)(m0 + row) * K + k0 + kg * 8;
                *(bf16x8*)&As[c * 8] = *(const bf16x8*)ap;
            } else {
                const float* ap = (const float*)Ap + (size_t)(m0 + row) * K + k0 + kg * 8;
                *(bf16x8*)&As[c * 8] = cvt2(*(const float4*)ap, *(const float4*)(ap + 4));
            }
        }
        __syncthreads();
        bf16x8 af[4], bfr[4];
        #pragma unroll
        for (int t = 0; t < 4; ++t) {
            af[t]  = *(const bf16x8*)&As[(wr * 64 + t * 16 + (lane & 15)) * BK + (lane >> 4) * 8];
            bfr[t] = *(const bf16x8*)&Bs[(wc * 64 + t * 16 + (lane & 15)) * BK + (lane >> 4) * 8];
        }
        #pragma unroll
        for (int mt = 0; mt < 4; ++mt)
            #pragma unroll
            for (int nt = 0; nt < 4; ++nt)
                acc[mt][nt] = __builtin_amdgcn_mfma_f32_16x16x32_bf16(af[mt], bfr[nt], acc[mt][nt], 0, 0, 0);
        __syncthreads();
    }

    // epilogue: D[row][col], row=(lane>>4)*4+r, col=lane&15 (verified m89/m91)
    #pragma unroll
    for (int mt = 0; mt < 4; ++mt) {
        #pragma unroll
        for (int nt = 0; nt < 4; ++nt) {
            const int mbase = m0 + wr * 64 + mt * 16 + ((lane >> 4) << 2);
            const int n     = n0 + wc * 64 + nt * 16 + (lane & 15);
            if constexpr (MODE == 0) {
                bf16* out = (bf16*)outp;
                const int h = n >> 6, dd = n & 63;
                #pragma unroll
                for (int r = 0; r < 4; ++r) {
                    const int m = mbase + r;
                    const int b = m >> 11, s = m & 2047;
                    out[(((size_t)(b * 16 + h)) * 2048 + s) * 64 + dd] = (bf16)acc[mt][nt][r];
                }
            } else if constexpr (MODE == 1) {
                bf16* out = (bf16*)outp;
                const int h = n >> 6, dd = n & 63;
                const int b = mbase >> 11, s = mbase & 2047;   // r=0..3 -> s..s+3 contiguous
                bf16x4 v4;
                #pragma unroll
                for (int r = 0; r < 4; ++r) v4[r] = (bf16)acc[mt][nt][r];
                *(bf16x4*)&out[(((size_t)(b * 16 + h)) * 64 + dd) * 2048 + s] = v4;
            } else {
                float* out = (float*)outp;
                #pragma unroll
                for (int r = 0; r < 4; ++r) {
                    const int m = mbase + r;
                    const size_t idx = (size_t)m * 1024 + n;
                    out[idx] = acc[mt][nt][r] + R[idx];
                }
            }
        }
    }
}

// =====================================================================
// Flash attention. block = 256 thr (4 waves), grid (S/128, H, B).
// Qp,Kp: [B,H,S,64] bf16. Vt: [B,H,64,S] bf16. ctx out: [B,S,H*64] bf16.
// =====================================================================
__global__ __launch_bounds__(256, 2)
void attn_kernel(const bf16* __restrict__ Qp, const bf16* __restrict__ Kp,
                 const bf16* __restrict__ Vt, const int* __restrict__ sen_len,
                 bf16* __restrict__ ctx)
{
    const int qt = blockIdx.x, h = blockIdx.y, b = blockIdx.z;
    const int q0 = qt * 128;
    const int bh = b * 16 + h;
    const int slen = sen_len[b];
    const int tid = threadIdx.x, lane = tid & 63, w = tid >> 6;
    const int wr = w >> 1, wc = w & 1;
    const float SCALE = 0.125f;   // 1/sqrt(64)

    __shared__ __align__(16) bf16 Ks[128 * 72];    // [k-row][d], 64->72 pad
    __shared__ __align__(16) bf16 Vs[64 * 136];    // [d][k-col], 128->136 pad
    __shared__ __align__(16) bf16 Ps[128 * 136];   // [q][k] probabilities
    __shared__ float m_run[128], l_run[128], pmax[2][128], psum[2][128];

    // Q fragments -> registers (A-operand: m=lane&15, k=(lane>>4)*8+j)
    bf16x8 qf[4][2];
    const bf16* Qbase = Qp + ((size_t)bh * 2048 + q0) * 64;
    #pragma unroll
    for (int mt = 0; mt < 4; ++mt)
        #pragma unroll
        for (int kk = 0; kk < 2; ++kk)
            qf[mt][kk] = *(const bf16x8*)(Qbase + (wr * 64 + mt * 16 + (lane & 15)) * 64
                                          + kk * 32 + (lane >> 4) * 8);

    f32x4 o[4][2] = {};
    if (tid < 128) { m_run[tid] = -3.0e38f; l_run[tid] = 0.0f; }

    const int jlim = min(q0 + 128, slen);
    const int nkt  = (jlim + 127) >> 7;       // >= 1 since slen >= 1

    for (int kt = 0; kt < nkt; ++kt) {
        const int k0 = kt * 128;
        // ---- stage K tile [128][64] and V^T tile [64][128] ----
        {
            const bf16* Kg = Kp + ((size_t)bh * 2048 + k0) * 64;
            #pragma unroll
            for (int i = 0; i < 4; ++i) {
                const int c = i * 256 + tid;
                const int row = c >> 3, cg = c & 7;
                *(bf16x8*)&Ks[row * 72 + cg * 8] = *(const bf16x8*)(Kg + row * 64 + cg * 8);
            }
            const bf16* Vg = Vt + (size_t)bh * 64 * 2048 + k0;
            #pragma unroll
            for (int i = 0; i < 4; ++i) {
                const int c = i * 256 + tid;
                const int row = c >> 4, cg = c & 15;
                *(bf16x8*)&Vs[row * 136 + cg * 8] = *(const bf16x8*)(Vg + (size_t)row * 2048 + cg * 8);
            }
        }
        __syncthreads();

        // ---- S = Q K^T ----
        f32x4 sf[4][4] = {};
        #pragma unroll
        for (int kk = 0; kk < 2; ++kk) {
            bf16x8 bk[4];
            #pragma unroll
            for (int nt = 0; nt < 4; ++nt)
                bk[nt] = *(const bf16x8*)&Ks[(wc * 64 + nt * 16 + (lane & 15)) * 72
                                             + kk * 32 + (lane >> 4) * 8];
            #pragma unroll
            for (int mt = 0; mt < 4; ++mt)
                #pragma unroll
                for (int nt = 0; nt < 4; ++nt)
                    sf[mt][nt] = __builtin_amdgcn_mfma_f32_16x16x32_bf16(qf[mt][kk], bk[nt], sf[mt][nt], 0, 0, 0);
        }

        // ---- scale + mask + per-wave row max ----
        float rmax[4][4];
        #pragma unroll
        for (int mt = 0; mt < 4; ++mt)
            #pragma unroll
            for (int r = 0; r < 4; ++r) {
                const int ig = q0 + wr * 64 + mt * 16 + ((lane >> 4) << 2) + r;
                float mx = -3.0e38f;
                #pragma unroll
                for (int nt = 0; nt < 4; ++nt) {
                    const int jg = k0 + wc * 64 + nt * 16 + (lane & 15);
                    float v = sf[mt][nt][r] * SCALE;
                    if (jg > ig || jg >= slen) v = -1.0e9f;
                    sf[mt][nt][r] = v;
                    mx = fmaxf(mx, v);
                }
                rmax[mt][r] = mx;
            }
        #pragma unroll
        for (int off = 1; off < 16; off <<= 1)
            #pragma unroll
            for (int mt = 0; mt < 4; ++mt)
                #pragma unroll
                for (int r = 0; r < 4; ++r)
                    rmax[mt][r] = fmaxf(rmax[mt][r], __shfl_xor(rmax[mt][r], off, 64));
        if ((lane & 15) == 0)
            #pragma unroll
            for (int mt = 0; mt < 4; ++mt)
                #pragma unroll
                for (int r = 0; r < 4; ++r)
                    pmax[wc][wr * 64 + mt * 16 + ((lane >> 4) << 2) + r] = rmax[mt][r];
        __syncthreads();

        // ---- P = exp(S - m_new), O *= alpha, partial sums ----
        float rsum[4][4], alpha_l[4][4];
        #pragma unroll
        for (int mt = 0; mt < 4; ++mt)
            #pragma unroll
            for (int r = 0; r < 4; ++r) {
                const int row = wr * 64 + mt * 16 + ((lane >> 4) << 2) + r;
                const float m_old = m_run[row];
                const float m_new = fmaxf(m_old, fmaxf(pmax[0][row], pmax[1][row]));
                alpha_l[mt][r] = __expf(m_old - m_new);
                float sum = 0.0f;
                #pragma unroll
                for (int nt = 0; nt < 4; ++nt) {
                    const float p = __expf(sf[mt][nt][r] - m_new);
                    sum += p;
                    Ps[row * 136 + wc * 64 + nt * 16 + (lane & 15)] = (bf16)p;
                }
                rsum[mt][r] = sum;
            }
        #pragma unroll
        for (int off = 1; off < 16; off <<= 1)
            #pragma unroll
            for (int mt = 0; mt < 4; ++mt)
                #pragma unroll
                for (int r = 0; r < 4; ++r)
                    rsum[mt][r] += __shfl_xor(rsum[mt][r], off, 64);
        if ((lane & 15) == 0)
            #pragma unroll
            for (int mt = 0; mt < 4; ++mt)
                #pragma unroll
                for (int r = 0; r < 4; ++r)
                    psum[wc][wr * 64 + mt * 16 + ((lane >> 4) << 2) + r] = rsum[mt][r];
        #pragma unroll
        for (int mt = 0; mt < 4; ++mt)
            #pragma unroll
            for (int nt = 0; nt < 2; ++nt)
                #pragma unroll
                for (int r = 0; r < 4; ++r)
                    o[mt][nt][r] *= alpha_l[mt][r];
        __syncthreads();

        // ---- stats update ----
        if (tid < 128) {
            const float m_old = m_run[tid];
            const float m_new = fmaxf(m_old, fmaxf(pmax[0][tid], pmax[1][tid]));
            m_run[tid] = m_new;
            l_run[tid] = l_run[tid] * __expf(m_old - m_new) + psum[0][tid] + psum[1][tid];
        }

        // ---- O += P V ----
        #pragma unroll
        for (int ks = 0; ks < 4; ++ks) {
            bf16x8 pf[4], vf[2];
            #pragma unroll
            for (int mt = 0; mt < 4; ++mt)
                pf[mt] = *(const bf16x8*)&Ps[(wr * 64 + mt * 16 + (lane & 15)) * 136
                                             + ks * 32 + (lane >> 4) * 8];
            #pragma unroll
            for (int nt = 0; nt < 2; ++nt)
                vf[nt] = *(const bf16x8*)&Vs[(wc * 32 + nt * 16 + (lane & 15)) * 136
                                             + ks * 32 + (lane >> 4) * 8];
            #pragma unroll
            for (int mt = 0; mt < 4; ++mt)
                #pragma unroll
                for (int nt = 0; nt < 2; ++nt)
                    o[mt][nt] = __builtin_amdgcn_mfma_f32_16x16x32_bf16(pf[mt], vf[nt], o[mt][nt], 0, 0, 0);
        }
        __syncthreads();
    }

    // ---- epilogue ----
    #pragma unroll
    for (int mt = 0; mt < 4; ++mt)
        #pragma unroll
        for (int r = 0; r < 4; ++r) {
            const int row = wr * 64 + mt * 16 + ((lane >> 4) << 2) + r;
            const float inv = 1.0f / l_run[row];
            const int sg = q0 + row;
            #pragma unroll
            for (int nt = 0; nt < 2; ++nt) {
                const int dd = wc * 32 + nt * 16 + (lane & 15);
                ctx[((size_t)(b * 2048 + sg)) * 1024 + h * 64 + dd] = (bf16)(o[mt][nt][r] * inv);
            }
        }
}

// =====================================================================
// LayerNorm over D=1024; y fp32 in, gamma/beta fp32, **fp32 out**.
// grid 8192, block 256.
// =====================================================================
__global__ __launch_bounds__(256)
void ln_kernel(const float* __restrict__ y, const float* __restrict__ gamma,
               const float* __restrict__ beta, float* __restrict__ out)
{
    const int row = blockIdx.x;
    const int tid = threadIdx.x;
    const float4 v = ((const float4*)(y + (size_t)row * 1024))[tid];
    float s  = v.x + v.y + v.z + v.w;
    float s2 = v.x * v.x + v.y * v.y + v.z * v.z + v.w * v.w;
    #pragma unroll
    for (int o = 32; o > 0; o >>= 1) {
        s  += __shfl_down(s, o, 64);
        s2 += __shfl_down(s2, o, 64);
    }
    __shared__ float ps[4], ps2[4], stat[2];
    const int w = tid >> 6, lane = tid & 63;
    if (lane == 0) { ps[w] = s; ps2[w] = s2; }
    __syncthreads();
    if (tid == 0) {
        const float S  = ps[0] + ps[1] + ps[2] + ps[3];
        const float S2 = ps2[0] + ps2[1] + ps2[2] + ps2[3];
        const float mean = S * (1.0f / 1024.0f);
        const float var  = S2 * (1.0f / 1024.0f) - mean * mean;
        stat[0] = mean;
        stat[1] = rsqrtf(var + 1e-5f);
    }
    __syncthreads();
    const float mean = stat[0], rstd = stat[1];
    float4 ov;
    ov.x = (v.x - mean) * rstd;
    ov.y = (v.y - mean) * rstd;
    ov.z = (v.z - mean) * rstd;
    ov.w = (v.w - mean) * rstd;
    const float4 g4 = ((const float4*)gamma)[tid];
    const float4 b4 = ((const float4*)beta)[tid];
    ov.x = ov.x * g4.x + b4.x;
    ov.y = ov.y * g4.y + b4.y;
    ov.z = ov.z * g4.z + b4.z;
    ov.w = ov.w * g4.w + b4.w;
    ((float4*)(out + (size_t)row * 1024))[tid] = ov;
}

// =====================================================================
extern "C" void kernel_launch(void* const* d_in, const int* in_sizes, int n_in,
                              void* d_out, int out_size, void* d_ws, size_t ws_size,
                              hipStream_t stream)
{
    const float* q     = (const float*)d_in[0];
    const float* k     = (const float*)d_in[1];
    const float* v     = (const float*)d_in[2];
    const float* Wq    = (const float*)d_in[3];
    const float* Wk    = (const float*)d_in[4];
    const float* Wv    = (const float*)d_in[5];
    const float* Wo    = (const float*)d_in[6];
    const float* gamma = (const float*)d_in[7];
    const float* beta  = (const float*)d_in[8];
    const int*   sen   = (const int*)d_in[9];

    char* ws = (char*)d_ws;
    const size_t SEG = 16777216;             // 8192*1024*2 bytes
    bf16* Qp  = (bf16*)(ws);
    bf16* Kp  = (bf16*)(ws + SEG);
    bf16* Vt  = (bf16*)(ws + 2 * SEG);
    bf16* ctx = (bf16*)(ws + 3 * SEG);
    float* y  = (float*)ws;                  // overlaps Qp/Kp (dead by then); 32 MB

    dim3 gg(8, 64), bb(256);
    gemm_bt<0><<<gg, bb, 0, stream>>>(q, Wq, nullptr, (void*)Qp);
    gemm_bt<0><<<gg, bb, 0, stream>>>(k, Wk, nullptr, (void*)Kp);
    gemm_bt<1><<<gg, bb, 0, stream>>>(v, Wv, nullptr, (void*)Vt);
    attn_kernel<<<dim3(16, 16, 4), bb, 0, stream>>>(Qp, Kp, Vt, sen, ctx);
    gemm_bt<2><<<gg, bb, 0, stream>>>(ctx, Wo, q, (void*)y);
    ln_kernel<<<dim3(8192), bb, 0, stream>>>(y, gamma, beta, (float*)d_out);
}